// Round 8
// baseline (238.910 us; speedup 1.0000x reference)
//
#include <hip/hip_runtime.h>

// B=16, T=2048, C=200, H=64 attention head with padding mask.
// Round 8: (a) qkv reverted to r6 (prep_w + b128-staged WtF->LDS: ~10us; r7's fused
// per-element repack cost ~38us). (b) attn: keep 128q/wave reuse (L1 bytes 512KB/CU)
// but restore 2 waves/SIMD: 512-thread blocks, 8 waves = key-split 8 x 256 keys,
// combine via LDS f32 atomicAdd. ~51us of dur_us is harness fill/gap floor.

typedef __attribute__((ext_vector_type(8))) __bf16 bf16x8;
typedef __attribute__((ext_vector_type(4))) __bf16 bf16x4;
typedef __attribute__((ext_vector_type(4))) float f32x4;

#define T_SEQ 2048
#define C_DIM 200
#define H_DIM 64
#define BT_TOT 32768
#define QKV_ELEMS 2097152
#define PPAD 72            // P row pad (bf16): 2-way bank alias only (free)
#define OPAD 68            // combine row pad (f32)
#define WTF_FULL 36864     // ks 0..5 full chunks: 6 * (3w*4t) * 512
#define WTF_ELEMS 38400    // + compact ks=6 chunk: 3*4*128 (c=192..199 only)
#define WTF_A_ELEMS 24576  // ks 0..3 (phase A, 48KB)
#define LOG2E 1.44269504088896f

// ---------------- Kernel 0: repack weights, compact MFMA fragment order ----------------
// Full chunk (ks<6, w, t): 512 bf16, elem lane*8+j = W_w[c=ks*32+(lane>>4)*8+j][h=t*16+(lane&15)]
// Compact ks=6 chunk (w, t): 128 bf16, elem l15*8+j = W_w[c=192+j][h=t*16+l15].
// w0 = Wq * (H^-0.5 * log2 e): scores land in log2 domain.
__global__ void prep_w(const float* __restrict__ Wk, const float* __restrict__ Wq,
                       const float* __restrict__ Wv, __bf16* __restrict__ WtF) {
    int idx = blockIdx.x * 256 + threadIdx.x;
    if (idx >= WTF_ELEMS) return;
    int w, c, h;
    if (idx < WTF_FULL) {
        int j = idx & 7, lane = (idx >> 3) & 63;
        int chunk = idx >> 9;                 // ks*12 + w*4 + t
        int t = chunk & 3, rest = chunk >> 2; // ks*3 + w
        w = rest % 3; int ks = rest / 3;
        c = ks * 32 + (lane >> 4) * 8 + j;
        h = t * 16 + (lane & 15);
    } else {
        int i2 = idx - WTF_FULL;
        int j = i2 & 7, l15 = (i2 >> 3) & 15, t = (i2 >> 7) & 3;
        w = i2 >> 9;
        c = 192 + j;
        h = t * 16 + l15;
    }
    const float* W = (w == 0) ? Wq : (w == 1) ? Wk : Wv;  // [C][H]
    float val = W[c * H_DIM + h];
    if (w == 0) val *= 0.125f * LOG2E;
    WtF[idx] = (__bf16)val;
}

// ---------------- Kernel 1: QKV projection (r6 structure) ----------------
// grid = 512 blocks x 256 threads (4 waves x 16 rows = 64 rows/block), 2 waves/SIMD.
// W staged in LDS via b128 copies (two phases, 48KB); x direct-from-global A-fragments;
// vT via LDS transpose for coalesced b128 stores.
__global__ __launch_bounds__(256) void qkv_proj(const float* __restrict__ x,
                                                const __bf16* __restrict__ WtF,
                                                __bf16* __restrict__ qb,
                                                __bf16* __restrict__ kb,
                                                __bf16* __restrict__ vT) {
    __shared__ __bf16 Wl[WTF_A_ELEMS];  // 49152 B; reused phase B + transpose epilogue

    const int tid = threadIdx.x;
    const int wave = tid >> 6, lane = tid & 63, l15 = lane & 15, quad = lane >> 4;
    const int m0b = blockIdx.x * 64;
    const int row0 = m0b + wave * 16;

    f32x4 acc[3][4] = {};  // [w][h-tile], 16 rows per wave

    // ---- phase A: stage ks 0..3 (3072 x 16B over 256 threads = 12 iters), compute ----
    #pragma unroll
    for (int i = 0; i < 12; ++i) {
        const int c = i * 256 + tid;
        *(bf16x8*)(Wl + c * 8) = *(const bf16x8*)(WtF + c * 8);
    }
    __syncthreads();
    #pragma unroll
    for (int ks = 0; ks < 4; ++ks) {
        const float* xr = x + (size_t)(row0 + l15) * C_DIM + ks * 32 + quad * 8;
        const float4 f0 = *(const float4*)xr;
        const float4 f1 = *(const float4*)(xr + 4);
        bf16x8 a;
        a[0]=(__bf16)f0.x; a[1]=(__bf16)f0.y; a[2]=(__bf16)f0.z; a[3]=(__bf16)f0.w;
        a[4]=(__bf16)f1.x; a[5]=(__bf16)f1.y; a[6]=(__bf16)f1.z; a[7]=(__bf16)f1.w;
        #pragma unroll
        for (int w = 0; w < 3; ++w)
            #pragma unroll
            for (int t = 0; t < 4; ++t) {
                const bf16x8 bf = *(const bf16x8*)(Wl + ((ks * 12 + w * 4 + t) << 9) + lane * 8);
                acc[w][t] = __builtin_amdgcn_mfma_f32_16x16x32_bf16(a, bf, acc[w][t], 0, 0, 0);
            }
    }
    __syncthreads();

    // ---- phase B: stage ks 4..6 (1728 x 16B = 7 guarded iters), compute ----
    #pragma unroll
    for (int i = 0; i < 7; ++i) {
        const int c = i * 256 + tid;
        if (c < 1728)
            *(bf16x8*)(Wl + c * 8) = *(const bf16x8*)(WtF + WTF_A_ELEMS + c * 8);
    }
    __syncthreads();
    #pragma unroll
    for (int ks = 4; ks < 7; ++ks) {
        bf16x8 a;
        if (ks < 6 || quad == 0) {
            // ks=6,quad0 reads c 192..199 exactly (in-bounds); other quads c>=200 -> A=0
            const float* xr = x + (size_t)(row0 + l15) * C_DIM + ks * 32 + quad * 8;
            const float4 f0 = *(const float4*)xr;
            const float4 f1 = *(const float4*)(xr + 4);
            a[0]=(__bf16)f0.x; a[1]=(__bf16)f0.y; a[2]=(__bf16)f0.z; a[3]=(__bf16)f0.w;
            a[4]=(__bf16)f1.x; a[5]=(__bf16)f1.y; a[6]=(__bf16)f1.z; a[7]=(__bf16)f1.w;
        } else {
            #pragma unroll
            for (int j = 0; j < 8; ++j) a[j] = (__bf16)0.f;
        }
        #pragma unroll
        for (int w = 0; w < 3; ++w)
            #pragma unroll
            for (int t = 0; t < 4; ++t) {
                // ks=6: compact chunk; quads 1..3 read quad0's data -> harmless (A rows 0)
                const int off = (ks < 6) ? (((ks - 4) * 12 + w * 4 + t) << 9) + lane * 8
                                         : 12288 + ((w * 4 + t) << 7) + l15 * 8;
                const bf16x8 bf = *(const bf16x8*)(Wl + off);
                acc[w][t] = __builtin_amdgcn_mfma_f32_16x16x32_bf16(a, bf, acc[w][t], 0, 0, 0);
            }
    }

    // ---- epilogue: q,k direct stores; vT via LDS transpose for coalesced b128 ----
    #pragma unroll
    for (int t = 0; t < 4; ++t)
        #pragma unroll
        for (int r = 0; r < 4; ++r) {
            const size_t m = row0 + quad * 4 + r;
            qb[m * H_DIM + t * 16 + l15] = (__bf16)acc[0][t][r];
            kb[m * H_DIM + t * 16 + l15] = (__bf16)acc[1][t][r];
        }
    __syncthreads();
    #pragma unroll
    for (int t = 0; t < 4; ++t)
        #pragma unroll
        for (int r = 0; r < 4; ++r)
            Wl[(t * 16 + l15) * 72 + wave * 16 + quad * 4 + r] = (__bf16)acc[2][t][r];
    __syncthreads();
    const int bb = m0b >> 11, tloc = m0b & 2047;
    #pragma unroll
    for (int i = 0; i < 2; ++i) {
        const int seg = i * 256 + tid;          // 512 segs: h row, 8-elem column chunk
        const int h = seg >> 3, s8 = seg & 7;
        *(bf16x8*)(vT + ((size_t)bb * H_DIM + h) * T_SEQ + tloc + s8 * 8) =
            *(const bf16x8*)(Wl + h * 72 + s8 * 8);
    }
}

// ---------------- Kernel 2: attention, 128 queries/wave, 8 waves/block ----------------
// grid = (T/128, B) = 256 blocks (1/CU); block = 512 (8 waves = 8 key-splits of 256
// keys, all over the same 128-q tile) -> 2 waves/SIMD for latency overlap, same K/V
// reuse as r7 (each fragment feeds 8 m-tiles). No-max softmax in log2 domain (S~N(0,1):
// fp32-safe; masked keys -> exp2(-1e30) = exact 0). Combine via LDS f32 atomicAdd.
__global__ __launch_bounds__(512, 2) void attn(const __bf16* __restrict__ qb,
                                               const __bf16* __restrict__ kb,
                                               const __bf16* __restrict__ vT,
                                               const int* __restrict__ pm,
                                               float* __restrict__ out) {
    // arena: [0,8K) key bias f32[2048]; [8K,+147456) per-wave P (8 x 128 x PPAD bf16),
    // unioned with combine region Ocomb[128][OPAD] f32 + Lcomb[128] f32 (35328 B).
    __shared__ __align__(16) char arena[8192 + 8 * 128 * PPAD * 2];
    float* biasS = (float*)arena;

    const int tid = threadIdx.x;
    const int wave = tid >> 6, lane = tid & 63, l15 = lane & 15, quad = lane >> 4;
    const int ks = wave;               // key split: 256 keys each
    const int b = blockIdx.y;
    const int q0 = blockIdx.x * 128;
    const size_t bT = (size_t)b * T_SEQ;

    {   // 512 threads x int4 covers all 2048 mask ints
        const int4 p4 = *(const int4*)(pm + bT + tid * 4);
        biasS[tid * 4 + 0] = p4.x ? 0.f : -1e30f;
        biasS[tid * 4 + 1] = p4.y ? 0.f : -1e30f;
        biasS[tid * 4 + 2] = p4.z ? 0.f : -1e30f;
        biasS[tid * 4 + 3] = p4.w ? 0.f : -1e30f;
    }
    __syncthreads();

    // Q fragments: qa[mt][s], lane holds Q[q0+mt*16+l15][s*32+quad*8 ..+8]
    bf16x8 qa[8][2];
    #pragma unroll
    for (int mt = 0; mt < 8; ++mt)
        #pragma unroll
        for (int s = 0; s < 2; ++s)
            qa[mt][s] = *(const bf16x8*)(qb + (bT + q0 + mt * 16 + l15) * H_DIM + s * 32 + quad * 8);

    __bf16* P = (__bf16*)(arena + 8192) + wave * (128 * PPAD);
    const __bf16* kbase = kb + bT * H_DIM;
    const __bf16* vbase = vT + (size_t)b * H_DIM * T_SEQ;

    f32x4 oacc[8][4] = {};   // O'[qtile][h-tile][row=quad*4+r]
    float lsum[8] = {};

    for (int kt = 0; kt < 4; ++kt) {
        const int key0 = ks * 256 + kt * 64;

        // S'^T per n-block: 8 q-tiles share each K fragment; exp; P -> LDS
        #pragma unroll
        for (int n = 0; n < 4; ++n) {
            const f32x4 bias = *(const f32x4*)(biasS + key0 + n * 16 + quad * 4);
            bf16x8 kf[2];
            #pragma unroll
            for (int s = 0; s < 2; ++s)
                kf[s] = *(const bf16x8*)(kbase + (key0 + n * 16 + l15) * H_DIM + s * 32 + quad * 8);
            f32x4 s_[8];
            #pragma unroll
            for (int mt = 0; mt < 8; ++mt) s_[mt] = bias;
            #pragma unroll
            for (int s = 0; s < 2; ++s)
                #pragma unroll
                for (int mt = 0; mt < 8; ++mt)
                    s_[mt] = __builtin_amdgcn_mfma_f32_16x16x32_bf16(kf[s], qa[mt][s], s_[mt], 0, 0, 0);
            #pragma unroll
            for (int mt = 0; mt < 8; ++mt) {
                bf16x4 p4;
                #pragma unroll
                for (int r = 0; r < 4; ++r) {
                    const float e = exp2f(s_[mt][r]);
                    lsum[mt] += e;
                    p4[r] = (__bf16)e;
                }
                *(bf16x4*)(P + (mt * 16 + l15) * PPAD + n * 16 + quad * 4) = p4;
            }
        }

        // re-read P as A-operand (per-wave buffer; DS in-order within wave -> no barrier)
        bf16x8 pa[8][2];
        #pragma unroll
        for (int mt = 0; mt < 8; ++mt)
            #pragma unroll
            for (int s = 0; s < 2; ++s)
                pa[mt][s] = *(const bf16x8*)(P + (mt * 16 + l15) * PPAD + s * 32 + quad * 8);

        // O' += P V, V fragment shared across 8 q-tiles
        #pragma unroll
        for (int t = 0; t < 4; ++t) {
            bf16x8 vf[2];
            #pragma unroll
            for (int s = 0; s < 2; ++s)
                vf[s] = *(const bf16x8*)(vbase + (size_t)(t * 16 + l15) * T_SEQ + key0 + s * 32 + quad * 8);
            #pragma unroll
            for (int s = 0; s < 2; ++s)
                #pragma unroll
                for (int mt = 0; mt < 8; ++mt)
                    oacc[mt][t] = __builtin_amdgcn_mfma_f32_16x16x32_bf16(pa[mt][s], vf[s], oacc[mt][t], 0, 0, 0);
        }
    }

    // finish l per key-split: all lanes end with l(query = mt*16 + l15) for my keys
    #pragma unroll
    for (int mt = 0; mt < 8; ++mt) {
        lsum[mt] += __shfl_xor(lsum[mt], 16, 64);
        lsum[mt] += __shfl_xor(lsum[mt], 32, 64);
    }

    // combine: zero the accumulator region (aliases P; all P reads done), atomicAdd
    // all 8 partials, then each wave finalizes its own m-tile.
    float* Ocomb = (float*)(arena + 8192);   // [128][OPAD]
    float* Lcomb = Ocomb + 128 * OPAD;       // [128]

    __syncthreads();
    {
        f32x4* Z = (f32x4*)Ocomb;            // (128*OPAD + 128)/4 = 2208 vec4s
        const f32x4 zv = {0.f, 0.f, 0.f, 0.f};
        #pragma unroll
        for (int i = 0; i < 5; ++i) {
            const int idx = i * 512 + tid;
            if (idx < 2208) Z[idx] = zv;
        }
    }
    __syncthreads();
    #pragma unroll
    for (int mt = 0; mt < 8; ++mt) {
        #pragma unroll
        for (int t = 0; t < 4; ++t)
            #pragma unroll
            for (int r = 0; r < 4; ++r)
                atomicAdd(&Ocomb[(mt * 16 + quad * 4 + r) * OPAD + t * 16 + l15], oacc[mt][t][r]);
        if (quad == 0) atomicAdd(&Lcomb[mt * 16 + l15], lsum[mt]);
    }
    __syncthreads();

    {   // parallel finalize: wave w handles m-tile w
        const int mt = wave;
        #pragma unroll
        for (int r = 0; r < 4; ++r) {
            const int qpos = q0 + mt * 16 + quad * 4 + r;
            const float lv = Lcomb[mt * 16 + quad * 4 + r];   // broadcast LDS read
            const bool qvalid = biasS[qpos] == 0.f;           // query mask == pm[b][t]
            const float inv = (qvalid && lv > 0.f) ? 1.f / lv : 0.f;
            #pragma unroll
            for (int t = 0; t < 4; ++t)
                out[(bT + qpos) * H_DIM + t * 16 + l15] =
                    Ocomb[(mt * 16 + quad * 4 + r) * OPAD + t * 16 + l15] * inv;
        }
    }
}

extern "C" void kernel_launch(void* const* d_in, const int* in_sizes, int n_in,
                              void* d_out, int out_size, void* d_ws, size_t ws_size,
                              hipStream_t stream) {
    const float* x  = (const float*)d_in[0];
    const int* pm   = (const int*)d_in[1];
    const float* Wk = (const float*)d_in[2];
    const float* Wq = (const float*)d_in[3];
    const float* Wv = (const float*)d_in[4];
    float* out = (float*)d_out;

    // ws: qb | kb | vT (bf16, 4MB each) | WtF (76.8KB)
    __bf16* qb  = (__bf16*)d_ws;
    __bf16* kb  = qb + QKV_ELEMS;
    __bf16* vT  = kb + QKV_ELEMS;
    __bf16* WtF = vT + QKV_ELEMS;

    prep_w<<<dim3((WTF_ELEMS + 255) / 256), dim3(256), 0, stream>>>(Wk, Wq, Wv, WtF);
    qkv_proj<<<dim3(BT_TOT / 64), dim3(256), 0, stream>>>(x, WtF, qb, kb, vT);
    attn<<<dim3(T_SEQ / 128, 16), dim3(512), 0, stream>>>(qb, kb, vT, pm, out);
}

// Round 9
// 125.516 us; speedup vs baseline: 1.9034x; 1.9034x over previous
//
#include <hip/hip_runtime.h>

// B=16, T=2048, C=200, H=64 attention head with padding mask.
// Round 9: revert to r6 (best, 124.5us): prep_w + b128-staged WtF qkv; attn 64q/wave,
// 4-way in-block key split, 2 waves/SIMD. Changes vs r6, attn only:
//  (1) 128-key tiles (4 iters, not 8) -> 2x scheduling window, same op totals;
//  (2) parallel combine: 4 waves store partials to 4 LDS regions (aliasing P), one
//      barrier, each wave finalizes 16 rows (r6 used a 4-barrier sequential chain).
// r8 lesson: 128q/wave at 8-wave blocks spills (128 AGPR acc + frags > budget).
// ~77-80us of dur_us is harness window overhead (256MiB ws poison fill + input restore).

typedef __attribute__((ext_vector_type(8))) __bf16 bf16x8;
typedef __attribute__((ext_vector_type(4))) __bf16 bf16x4;
typedef __attribute__((ext_vector_type(4))) float f32x4;

#define T_SEQ 2048
#define C_DIM 200
#define H_DIM 64
#define BT_TOT 32768
#define QKV_ELEMS 2097152
#define PROW 136           // P row length (bf16): 128 keys + 8 pad (same bank pattern as r6)
#define OPAD 68            // combine row pad (f32)
#define WTF_FULL 36864     // ks 0..5 full chunks: 6 * (3w*4t) * 512
#define WTF_ELEMS 38400    // + compact ks=6 chunk: 3*4*128 (c=192..199 only)
#define WTF_A_ELEMS 24576  // ks 0..3 (phase A, 48KB)
#define LOG2E 1.44269504088896f

// ---------------- Kernel 0: repack weights, compact MFMA fragment order ----------------
// Full chunk (ks<6, w, t): 512 bf16, elem lane*8+j = W_w[c=ks*32+(lane>>4)*8+j][h=t*16+(lane&15)]
// Compact ks=6 chunk (w, t): 128 bf16, elem l15*8+j = W_w[c=192+j][h=t*16+l15].
// w0 = Wq * (H^-0.5 * log2 e): scores land in log2 domain.
__global__ void prep_w(const float* __restrict__ Wk, const float* __restrict__ Wq,
                       const float* __restrict__ Wv, __bf16* __restrict__ WtF) {
    int idx = blockIdx.x * 256 + threadIdx.x;
    if (idx >= WTF_ELEMS) return;
    int w, c, h;
    if (idx < WTF_FULL) {
        int j = idx & 7, lane = (idx >> 3) & 63;
        int chunk = idx >> 9;                 // ks*12 + w*4 + t
        int t = chunk & 3, rest = chunk >> 2; // ks*3 + w
        w = rest % 3; int ks = rest / 3;
        c = ks * 32 + (lane >> 4) * 8 + j;
        h = t * 16 + (lane & 15);
    } else {
        int i2 = idx - WTF_FULL;
        int j = i2 & 7, l15 = (i2 >> 3) & 15, t = (i2 >> 7) & 3;
        w = i2 >> 9;
        c = 192 + j;
        h = t * 16 + l15;
    }
    const float* W = (w == 0) ? Wq : (w == 1) ? Wk : Wv;  // [C][H]
    float val = W[c * H_DIM + h];
    if (w == 0) val *= 0.125f * LOG2E;
    WtF[idx] = (__bf16)val;
}

// ---------------- Kernel 1: QKV projection (r6 structure, unchanged) ----------------
// grid = 512 blocks x 256 threads (4 waves x 16 rows = 64 rows/block), 2 waves/SIMD.
// W staged in LDS via b128 copies (two phases, 48KB); x direct-from-global A-fragments;
// vT via LDS transpose for coalesced b128 stores.
__global__ __launch_bounds__(256) void qkv_proj(const float* __restrict__ x,
                                                const __bf16* __restrict__ WtF,
                                                __bf16* __restrict__ qb,
                                                __bf16* __restrict__ kb,
                                                __bf16* __restrict__ vT) {
    __shared__ __bf16 Wl[WTF_A_ELEMS];  // 49152 B; reused phase B + transpose epilogue

    const int tid = threadIdx.x;
    const int wave = tid >> 6, lane = tid & 63, l15 = lane & 15, quad = lane >> 4;
    const int m0b = blockIdx.x * 64;
    const int row0 = m0b + wave * 16;

    f32x4 acc[3][4] = {};  // [w][h-tile], 16 rows per wave

    // ---- phase A: stage ks 0..3 (3072 x 16B over 256 threads = 12 iters), compute ----
    #pragma unroll
    for (int i = 0; i < 12; ++i) {
        const int c = i * 256 + tid;
        *(bf16x8*)(Wl + c * 8) = *(const bf16x8*)(WtF + c * 8);
    }
    __syncthreads();
    #pragma unroll
    for (int ks = 0; ks < 4; ++ks) {
        const float* xr = x + (size_t)(row0 + l15) * C_DIM + ks * 32 + quad * 8;
        const float4 f0 = *(const float4*)xr;
        const float4 f1 = *(const float4*)(xr + 4);
        bf16x8 a;
        a[0]=(__bf16)f0.x; a[1]=(__bf16)f0.y; a[2]=(__bf16)f0.z; a[3]=(__bf16)f0.w;
        a[4]=(__bf16)f1.x; a[5]=(__bf16)f1.y; a[6]=(__bf16)f1.z; a[7]=(__bf16)f1.w;
        #pragma unroll
        for (int w = 0; w < 3; ++w)
            #pragma unroll
            for (int t = 0; t < 4; ++t) {
                const bf16x8 bf = *(const bf16x8*)(Wl + ((ks * 12 + w * 4 + t) << 9) + lane * 8);
                acc[w][t] = __builtin_amdgcn_mfma_f32_16x16x32_bf16(a, bf, acc[w][t], 0, 0, 0);
            }
    }
    __syncthreads();

    // ---- phase B: stage ks 4..6 (1728 x 16B = 7 guarded iters), compute ----
    #pragma unroll
    for (int i = 0; i < 7; ++i) {
        const int c = i * 256 + tid;
        if (c < 1728)
            *(bf16x8*)(Wl + c * 8) = *(const bf16x8*)(WtF + WTF_A_ELEMS + c * 8);
    }
    __syncthreads();
    #pragma unroll
    for (int ks = 4; ks < 7; ++ks) {
        bf16x8 a;
        if (ks < 6 || quad == 0) {
            // ks=6,quad0 reads c 192..199 exactly (in-bounds); other quads c>=200 -> A=0
            const float* xr = x + (size_t)(row0 + l15) * C_DIM + ks * 32 + quad * 8;
            const float4 f0 = *(const float4*)xr;
            const float4 f1 = *(const float4*)(xr + 4);
            a[0]=(__bf16)f0.x; a[1]=(__bf16)f0.y; a[2]=(__bf16)f0.z; a[3]=(__bf16)f0.w;
            a[4]=(__bf16)f1.x; a[5]=(__bf16)f1.y; a[6]=(__bf16)f1.z; a[7]=(__bf16)f1.w;
        } else {
            #pragma unroll
            for (int j = 0; j < 8; ++j) a[j] = (__bf16)0.f;
        }
        #pragma unroll
        for (int w = 0; w < 3; ++w)
            #pragma unroll
            for (int t = 0; t < 4; ++t) {
                // ks=6: compact chunk; quads 1..3 read quad0's data -> harmless (A rows 0)
                const int off = (ks < 6) ? (((ks - 4) * 12 + w * 4 + t) << 9) + lane * 8
                                         : 12288 + ((w * 4 + t) << 7) + l15 * 8;
                const bf16x8 bf = *(const bf16x8*)(Wl + off);
                acc[w][t] = __builtin_amdgcn_mfma_f32_16x16x32_bf16(a, bf, acc[w][t], 0, 0, 0);
            }
    }

    // ---- epilogue: q,k direct stores; vT via LDS transpose for coalesced b128 ----
    #pragma unroll
    for (int t = 0; t < 4; ++t)
        #pragma unroll
        for (int r = 0; r < 4; ++r) {
            const size_t m = row0 + quad * 4 + r;
            qb[m * H_DIM + t * 16 + l15] = (__bf16)acc[0][t][r];
            kb[m * H_DIM + t * 16 + l15] = (__bf16)acc[1][t][r];
        }
    __syncthreads();
    #pragma unroll
    for (int t = 0; t < 4; ++t)
        #pragma unroll
        for (int r = 0; r < 4; ++r)
            Wl[(t * 16 + l15) * 72 + wave * 16 + quad * 4 + r] = (__bf16)acc[2][t][r];
    __syncthreads();
    const int bb = m0b >> 11, tloc = m0b & 2047;
    #pragma unroll
    for (int i = 0; i < 2; ++i) {
        const int seg = i * 256 + tid;          // 512 segs: h row, 8-elem column chunk
        const int h = seg >> 3, s8 = seg & 7;
        *(bf16x8*)(vT + ((size_t)bb * H_DIM + h) * T_SEQ + tloc + s8 * 8) =
            *(const bf16x8*)(Wl + h * 72 + s8 * 8);
    }
}

// ---------------- Kernel 2: attention, 64 q/wave, 128-key tiles, parallel combine ----
// grid = (T/64, B) = 512 blocks (2/CU); block = 256 (4 waves = 4 key-splits of 512,
// same 64-q tile), 2 waves/SIMD. No-max softmax in log2 domain (S~N(0,1): fp32-safe;
// masked keys -> exp2(-1e30) = exact 0).
__global__ __launch_bounds__(256, 2) void attn(const __bf16* __restrict__ qb,
                                               const __bf16* __restrict__ kb,
                                               const __bf16* __restrict__ vT,
                                               const int* __restrict__ pm,
                                               float* __restrict__ out) {
    // arena: [0,8K) key bias f32[2048]; [8K, 8K+69632) per-wave P (4 x 64 x PROW bf16),
    // aliased after the K-loop by Ocomb[4][64][OPAD] f32 (exactly 69632 B); then
    // Lcomb[4][64] f32 (1KB). Total 78848 B -> 2 blocks/CU.
    __shared__ __align__(16) char arena[8192 + 69632 + 1024];
    float* biasS = (float*)arena;

    const int tid = threadIdx.x;
    const int wave = tid >> 6, lane = tid & 63, l15 = lane & 15, quad = lane >> 4;
    const int ks = wave;               // key split: 512 keys each, 4 tiles of 128
    const int b = blockIdx.y;
    const int q0 = blockIdx.x * 64;
    const size_t bT = (size_t)b * T_SEQ;

    for (int i = tid; i < 512; i += 256) {
        const int4 p4 = *(const int4*)(pm + bT + i * 4);
        biasS[i * 4 + 0] = p4.x ? 0.f : -1e30f;
        biasS[i * 4 + 1] = p4.y ? 0.f : -1e30f;
        biasS[i * 4 + 2] = p4.z ? 0.f : -1e30f;
        biasS[i * 4 + 3] = p4.w ? 0.f : -1e30f;
    }
    __syncthreads();

    // Q fragments: qa[mt][s], lane holds Q[q0+mt*16+l15][s*32+quad*8 ..+8]
    bf16x8 qa[4][2];
    #pragma unroll
    for (int mt = 0; mt < 4; ++mt)
        #pragma unroll
        for (int s = 0; s < 2; ++s)
            qa[mt][s] = *(const bf16x8*)(qb + (bT + q0 + mt * 16 + l15) * H_DIM + s * 32 + quad * 8);

    __bf16* P = (__bf16*)(arena + 8192) + wave * (64 * PROW);
    const __bf16* kbase = kb + bT * H_DIM;
    const __bf16* vbase = vT + (size_t)b * H_DIM * T_SEQ;

    f32x4 oacc[4][4] = {};   // O'[qtile][h-tile][row=quad*4+r]
    float lsum[4] = {};

    for (int kt = 0; kt < 4; ++kt) {
        const int key0 = ks * 512 + kt * 128;   // 128-key tile

        // S'^T per n-block (8 blocks of 16 keys): 4 q-tiles share each K fragment;
        // exp; P -> LDS rows [query][key 0..127]
        #pragma unroll
        for (int n = 0; n < 8; ++n) {
            const f32x4 bias = *(const f32x4*)(biasS + key0 + n * 16 + quad * 4);
            bf16x8 kf[2];
            #pragma unroll
            for (int s = 0; s < 2; ++s)
                kf[s] = *(const bf16x8*)(kbase + (key0 + n * 16 + l15) * H_DIM + s * 32 + quad * 8);
            f32x4 s_[4];
            #pragma unroll
            for (int mt = 0; mt < 4; ++mt) s_[mt] = bias;
            #pragma unroll
            for (int s = 0; s < 2; ++s)
                #pragma unroll
                for (int mt = 0; mt < 4; ++mt)
                    s_[mt] = __builtin_amdgcn_mfma_f32_16x16x32_bf16(kf[s], qa[mt][s], s_[mt], 0, 0, 0);
            #pragma unroll
            for (int mt = 0; mt < 4; ++mt) {
                bf16x4 p4;
                #pragma unroll
                for (int r = 0; r < 4; ++r) {
                    const float e = exp2f(s_[mt][r]);
                    lsum[mt] += e;
                    p4[r] = (__bf16)e;
                }
                *(bf16x4*)(P + (mt * 16 + l15) * PROW + n * 16 + quad * 4) = p4;
            }
        }

        // re-read P as A-operand (per-wave buffer; DS in-order within wave -> no barrier)
        bf16x8 pa[4][4];
        #pragma unroll
        for (int mt = 0; mt < 4; ++mt)
            #pragma unroll
            for (int s = 0; s < 4; ++s)
                pa[mt][s] = *(const bf16x8*)(P + (mt * 16 + l15) * PROW + s * 32 + quad * 8);

        // O' += P V over 4 k-steps of 32 keys; V fragment shared across 4 q-tiles
        #pragma unroll
        for (int t = 0; t < 4; ++t) {
            bf16x8 vf[4];
            #pragma unroll
            for (int s = 0; s < 4; ++s)
                vf[s] = *(const bf16x8*)(vbase + (size_t)(t * 16 + l15) * T_SEQ + key0 + s * 32 + quad * 8);
            #pragma unroll
            for (int s = 0; s < 4; ++s)
                #pragma unroll
                for (int mt = 0; mt < 4; ++mt)
                    oacc[mt][t] = __builtin_amdgcn_mfma_f32_16x16x32_bf16(pa[mt][s], vf[s], oacc[mt][t], 0, 0, 0);
        }
    }

    // finish l per key-split: all lanes end with l(query = mt*16 + l15) for my keys
    #pragma unroll
    for (int mt = 0; mt < 4; ++mt) {
        lsum[mt] += __shfl_xor(lsum[mt], 16, 64);
        lsum[mt] += __shfl_xor(lsum[mt], 32, 64);
    }

    // parallel combine: every wave stores its full 64-row partial into its own region
    // (aliases P; all P reads done), one barrier, then wave w finalizes rows [16w,16w+16).
    float* Ocomb = (float*)(arena + 8192);            // [4][64][OPAD]
    float* Lcomb = (float*)(arena + 8192 + 69632);    // [4][64]

    __syncthreads();
    {
        float* Ow = Ocomb + wave * (64 * OPAD);
        #pragma unroll
        for (int mt = 0; mt < 4; ++mt) {
            #pragma unroll
            for (int t = 0; t < 4; ++t)
                #pragma unroll
                for (int r = 0; r < 4; ++r)
                    Ow[(mt * 16 + quad * 4 + r) * OPAD + t * 16 + l15] = oacc[mt][t][r];
            if (quad == 0) Lcomb[wave * 64 + mt * 16 + l15] = lsum[mt];
        }
    }
    __syncthreads();
    {
        const int mt = wave;   // this wave finalizes queries [q0+16*wave, q0+16*wave+16)
        #pragma unroll
        for (int r = 0; r < 4; ++r) {
            const int rw = mt * 16 + quad * 4 + r;
            const int qpos = q0 + rw;
            float lv = 0.f;
            #pragma unroll
            for (int wv = 0; wv < 4; ++wv) lv += Lcomb[wv * 64 + rw];
            const bool qvalid = biasS[qpos] == 0.f;   // query mask == pm[b][t]
            const float inv = (qvalid && lv > 0.f) ? 1.f / lv : 0.f;
            #pragma unroll
            for (int t = 0; t < 4; ++t) {
                float o = 0.f;
                #pragma unroll
                for (int wv = 0; wv < 4; ++wv)
                    o += Ocomb[wv * (64 * OPAD) + rw * OPAD + t * 16 + l15];
                out[(bT + qpos) * H_DIM + t * 16 + l15] = o * inv;
            }
        }
    }
}

extern "C" void kernel_launch(void* const* d_in, const int* in_sizes, int n_in,
                              void* d_out, int out_size, void* d_ws, size_t ws_size,
                              hipStream_t stream) {
    const float* x  = (const float*)d_in[0];
    const int* pm   = (const int*)d_in[1];
    const float* Wk = (const float*)d_in[2];
    const float* Wq = (const float*)d_in[3];
    const float* Wv = (const float*)d_in[4];
    float* out = (float*)d_out;

    // ws: qb | kb | vT (bf16, 4MB each) | WtF (76.8KB)
    __bf16* qb  = (__bf16*)d_ws;
    __bf16* kb  = qb + QKV_ELEMS;
    __bf16* vT  = kb + QKV_ELEMS;
    __bf16* WtF = vT + QKV_ELEMS;

    prep_w<<<dim3((WTF_ELEMS + 255) / 256), dim3(256), 0, stream>>>(Wk, Wq, Wv, WtF);
    qkv_proj<<<dim3(BT_TOT / 64), dim3(256), 0, stream>>>(x, WtF, qb, kb, vT);
    attn<<<dim3(T_SEQ / 64, 16), dim3(256), 0, stream>>>(qb, kb, vT, pm, out);
}

// Round 10
// 125.243 us; speedup vs baseline: 1.9076x; 1.0022x over previous
//
#include <hip/hip_runtime.h>

// B=16, T=2048, C=200, H=64 attention head with padding mask.
// Round 10 (base r9): (a) attn: l = P*ones via MFMA (16 extra MFMA/kt on the 14%-busy
// matrix pipe) replaces 128 v_add/kt/lane + end shuffles on the 34%-busy VALU chain;
// (b) qkv: q,k,v all exit through LDS (one barrier pair, 3 x 64x72 regions) as b128
// coalesced stores, replacing 4096 scalar 2B q/k stores per block.
// Measured context (r9): attn clock ~0.8GHz; per-CU cycles: L1-return 46%, VALU 34%,
// MFMA 14%. ~55-60us of dur_us is harness window overhead (ws poison fill + restores).

typedef __attribute__((ext_vector_type(8))) __bf16 bf16x8;
typedef __attribute__((ext_vector_type(4))) __bf16 bf16x4;
typedef __attribute__((ext_vector_type(4))) float f32x4;

#define T_SEQ 2048
#define C_DIM 200
#define H_DIM 64
#define BT_TOT 32768
#define QKV_ELEMS 2097152
#define PROW 136           // P row length (bf16): 128 keys + 8 pad
#define OPAD 68            // combine row pad (f32)
#define WTF_FULL 36864     // ks 0..5 full chunks: 6 * (3w*4t) * 512
#define WTF_ELEMS 38400    // + compact ks=6 chunk: 3*4*128 (c=192..199 only)
#define WTF_A_ELEMS 24576  // ks 0..3 (phase A, 48KB)
#define LOG2E 1.44269504088896f

// ---------------- Kernel 0: repack weights, compact MFMA fragment order ----------------
// Full chunk (ks<6, w, t): 512 bf16, elem lane*8+j = W_w[c=ks*32+(lane>>4)*8+j][h=t*16+(lane&15)]
// Compact ks=6 chunk (w, t): 128 bf16, elem l15*8+j = W_w[c=192+j][h=t*16+l15].
// w0 = Wq * (H^-0.5 * log2 e): scores land in log2 domain.
__global__ void prep_w(const float* __restrict__ Wk, const float* __restrict__ Wq,
                       const float* __restrict__ Wv, __bf16* __restrict__ WtF) {
    int idx = blockIdx.x * 256 + threadIdx.x;
    if (idx >= WTF_ELEMS) return;
    int w, c, h;
    if (idx < WTF_FULL) {
        int j = idx & 7, lane = (idx >> 3) & 63;
        int chunk = idx >> 9;                 // ks*12 + w*4 + t
        int t = chunk & 3, rest = chunk >> 2; // ks*3 + w
        w = rest % 3; int ks = rest / 3;
        c = ks * 32 + (lane >> 4) * 8 + j;
        h = t * 16 + (lane & 15);
    } else {
        int i2 = idx - WTF_FULL;
        int j = i2 & 7, l15 = (i2 >> 3) & 15, t = (i2 >> 7) & 3;
        w = i2 >> 9;
        c = 192 + j;
        h = t * 16 + l15;
    }
    const float* W = (w == 0) ? Wq : (w == 1) ? Wk : Wv;  // [C][H]
    float val = W[c * H_DIM + h];
    if (w == 0) val *= 0.125f * LOG2E;
    WtF[idx] = (__bf16)val;
}

// ---------------- Kernel 1: QKV projection ----------------
// grid = 512 blocks x 256 threads (4 waves x 16 rows = 64 rows/block), 2 waves/SIMD.
// W staged in LDS via b128 copies (two phases, 48KB); x direct-from-global A-fragments;
// epilogue: q,k,v ALL through LDS (3 x 64x72 regions, one barrier pair) -> b128 stores.
__global__ __launch_bounds__(256) void qkv_proj(const float* __restrict__ x,
                                                const __bf16* __restrict__ WtF,
                                                __bf16* __restrict__ qb,
                                                __bf16* __restrict__ kb,
                                                __bf16* __restrict__ vT) {
    __shared__ __bf16 Wl[WTF_A_ELEMS];  // 49152 B; reused by phase B + epilogue regions

    const int tid = threadIdx.x;
    const int wave = tid >> 6, lane = tid & 63, l15 = lane & 15, quad = lane >> 4;
    const int m0b = blockIdx.x * 64;
    const int row0 = m0b + wave * 16;

    f32x4 acc[3][4] = {};  // [w][h-tile], 16 rows per wave

    // ---- phase A: stage ks 0..3 (3072 x 16B over 256 threads = 12 iters), compute ----
    #pragma unroll
    for (int i = 0; i < 12; ++i) {
        const int c = i * 256 + tid;
        *(bf16x8*)(Wl + c * 8) = *(const bf16x8*)(WtF + c * 8);
    }
    __syncthreads();
    #pragma unroll
    for (int ks = 0; ks < 4; ++ks) {
        const float* xr = x + (size_t)(row0 + l15) * C_DIM + ks * 32 + quad * 8;
        const float4 f0 = *(const float4*)xr;
        const float4 f1 = *(const float4*)(xr + 4);
        bf16x8 a;
        a[0]=(__bf16)f0.x; a[1]=(__bf16)f0.y; a[2]=(__bf16)f0.z; a[3]=(__bf16)f0.w;
        a[4]=(__bf16)f1.x; a[5]=(__bf16)f1.y; a[6]=(__bf16)f1.z; a[7]=(__bf16)f1.w;
        #pragma unroll
        for (int w = 0; w < 3; ++w)
            #pragma unroll
            for (int t = 0; t < 4; ++t) {
                const bf16x8 bf = *(const bf16x8*)(Wl + ((ks * 12 + w * 4 + t) << 9) + lane * 8);
                acc[w][t] = __builtin_amdgcn_mfma_f32_16x16x32_bf16(a, bf, acc[w][t], 0, 0, 0);
            }
    }
    __syncthreads();

    // ---- phase B: stage ks 4..6 (1728 x 16B = 7 guarded iters), compute ----
    #pragma unroll
    for (int i = 0; i < 7; ++i) {
        const int c = i * 256 + tid;
        if (c < 1728)
            *(bf16x8*)(Wl + c * 8) = *(const bf16x8*)(WtF + WTF_A_ELEMS + c * 8);
    }
    __syncthreads();
    #pragma unroll
    for (int ks = 4; ks < 7; ++ks) {
        bf16x8 a;
        if (ks < 6 || quad == 0) {
            // ks=6,quad0 reads c 192..199 exactly (in-bounds); other quads c>=200 -> A=0
            const float* xr = x + (size_t)(row0 + l15) * C_DIM + ks * 32 + quad * 8;
            const float4 f0 = *(const float4*)xr;
            const float4 f1 = *(const float4*)(xr + 4);
            a[0]=(__bf16)f0.x; a[1]=(__bf16)f0.y; a[2]=(__bf16)f0.z; a[3]=(__bf16)f0.w;
            a[4]=(__bf16)f1.x; a[5]=(__bf16)f1.y; a[6]=(__bf16)f1.z; a[7]=(__bf16)f1.w;
        } else {
            #pragma unroll
            for (int j = 0; j < 8; ++j) a[j] = (__bf16)0.f;
        }
        #pragma unroll
        for (int w = 0; w < 3; ++w)
            #pragma unroll
            for (int t = 0; t < 4; ++t) {
                // ks=6: compact chunk; quads 1..3 read quad0's data -> harmless (A rows 0)
                const int off = (ks < 6) ? (((ks - 4) * 12 + w * 4 + t) << 9) + lane * 8
                                         : 12288 + ((w * 4 + t) << 7) + l15 * 8;
                const bf16x8 bf = *(const bf16x8*)(Wl + off);
                acc[w][t] = __builtin_amdgcn_mfma_f32_16x16x32_bf16(a, bf, acc[w][t], 0, 0, 0);
            }
    }

    // ---- epilogue: q,k row-major + v transposed through LDS; b128 coalesced stores ----
    __syncthreads();   // all waves done reading Wl for MFMA
    {
        __bf16* Lq = Wl;            // [64][72]
        __bf16* Lk = Wl + 4608;     // [64][72]
        __bf16* Lv = Wl + 9216;     // [64][72], transposed [h][m]
        #pragma unroll
        for (int t = 0; t < 4; ++t)
            #pragma unroll
            for (int r = 0; r < 4; ++r) {
                const int mloc = wave * 16 + quad * 4 + r;
                Lq[mloc * 72 + t * 16 + l15] = (__bf16)acc[0][t][r];
                Lk[mloc * 72 + t * 16 + l15] = (__bf16)acc[1][t][r];
                Lv[(t * 16 + l15) * 72 + mloc] = (__bf16)acc[2][t][r];
            }
    }
    __syncthreads();
    {
        const int bb = m0b >> 11, tloc = m0b & 2047;
        #pragma unroll
        for (int i = 0; i < 2; ++i) {
            const int seg = i * 256 + tid;       // 512 segs: row, 8-elem column chunk
            const int row = seg >> 3, s8 = seg & 7;
            *(bf16x8*)(qb + (size_t)(m0b + row) * H_DIM + s8 * 8) =
                *(const bf16x8*)(Wl + row * 72 + s8 * 8);
            *(bf16x8*)(kb + (size_t)(m0b + row) * H_DIM + s8 * 8) =
                *(const bf16x8*)(Wl + 4608 + row * 72 + s8 * 8);
            *(bf16x8*)(vT + ((size_t)bb * H_DIM + row) * T_SEQ + tloc + s8 * 8) =
                *(const bf16x8*)(Wl + 9216 + row * 72 + s8 * 8);
        }
    }
}

// ---------------- Kernel 2: attention, 64 q/wave, 128-key tiles ----------------
// grid = (T/64, B) = 512 blocks (2/CU); block = 256 (4 waves = 4 key-splits of 512,
// same 64-q tile), 2 waves/SIMD. No-max softmax in log2 domain (S~N(0,1): fp32-safe;
// masked keys -> exp2(-1e30) = exact 0). Row-sums l computed on the MFMA pipe
// (P * ones-fragment) instead of the VALU chain.
__global__ __launch_bounds__(256, 2) void attn(const __bf16* __restrict__ qb,
                                               const __bf16* __restrict__ kb,
                                               const __bf16* __restrict__ vT,
                                               const int* __restrict__ pm,
                                               float* __restrict__ out) {
    // arena: [0,8K) key bias f32[2048]; [8K, 8K+69632) per-wave P (4 x 64 x PROW bf16),
    // aliased after the K-loop by Ocomb[4][64][OPAD] f32; then Lcomb[4][64] f32 (1KB).
    __shared__ __align__(16) char arena[8192 + 69632 + 1024];
    float* biasS = (float*)arena;

    const int tid = threadIdx.x;
    const int wave = tid >> 6, lane = tid & 63, l15 = lane & 15, quad = lane >> 4;
    const int ks = wave;               // key split: 512 keys each, 4 tiles of 128
    const int b = blockIdx.y;
    const int q0 = blockIdx.x * 64;
    const size_t bT = (size_t)b * T_SEQ;

    for (int i = tid; i < 512; i += 256) {
        const int4 p4 = *(const int4*)(pm + bT + i * 4);
        biasS[i * 4 + 0] = p4.x ? 0.f : -1e30f;
        biasS[i * 4 + 1] = p4.y ? 0.f : -1e30f;
        biasS[i * 4 + 2] = p4.z ? 0.f : -1e30f;
        biasS[i * 4 + 3] = p4.w ? 0.f : -1e30f;
    }
    __syncthreads();

    // Q fragments: qa[mt][s], lane holds Q[q0+mt*16+l15][s*32+quad*8 ..+8]
    bf16x8 qa[4][2];
    #pragma unroll
    for (int mt = 0; mt < 4; ++mt)
        #pragma unroll
        for (int s = 0; s < 2; ++s)
            qa[mt][s] = *(const bf16x8*)(qb + (bT + q0 + mt * 16 + l15) * H_DIM + s * 32 + quad * 8);

    // all-ones B fragment for row-sum MFMAs
    bf16x8 ones;
    #pragma unroll
    for (int j = 0; j < 8; ++j) ones[j] = (__bf16)1.0f;

    __bf16* P = (__bf16*)(arena + 8192) + wave * (64 * PROW);
    const __bf16* kbase = kb + bT * H_DIM;
    const __bf16* vbase = vT + (size_t)b * H_DIM * T_SEQ;

    f32x4 oacc[4][4] = {};   // O'[qtile][h-tile][row=quad*4+r]
    f32x4 oaccL[4] = {};     // row-sums l' in C/D layout: [qtile][row=quad*4+r]

    for (int kt = 0; kt < 4; ++kt) {
        const int key0 = ks * 512 + kt * 128;   // 128-key tile

        // S'^T per n-block (8 blocks of 16 keys): 4 q-tiles share each K fragment;
        // exp; P -> LDS rows [query][key 0..127]
        #pragma unroll
        for (int n = 0; n < 8; ++n) {
            const f32x4 bias = *(const f32x4*)(biasS + key0 + n * 16 + quad * 4);
            bf16x8 kf[2];
            #pragma unroll
            for (int s = 0; s < 2; ++s)
                kf[s] = *(const bf16x8*)(kbase + (key0 + n * 16 + l15) * H_DIM + s * 32 + quad * 8);
            f32x4 s_[4];
            #pragma unroll
            for (int mt = 0; mt < 4; ++mt) s_[mt] = bias;
            #pragma unroll
            for (int s = 0; s < 2; ++s)
                #pragma unroll
                for (int mt = 0; mt < 4; ++mt)
                    s_[mt] = __builtin_amdgcn_mfma_f32_16x16x32_bf16(kf[s], qa[mt][s], s_[mt], 0, 0, 0);
            #pragma unroll
            for (int mt = 0; mt < 4; ++mt) {
                bf16x4 p4;
                #pragma unroll
                for (int r = 0; r < 4; ++r)
                    p4[r] = (__bf16)exp2f(s_[mt][r]);
                *(bf16x4*)(P + (mt * 16 + l15) * PROW + n * 16 + quad * 4) = p4;
            }
        }

        // re-read P as A-operand (per-wave buffer; DS in-order within wave -> no barrier)
        bf16x8 pa[4][4];
        #pragma unroll
        for (int mt = 0; mt < 4; ++mt)
            #pragma unroll
            for (int s = 0; s < 4; ++s)
                pa[mt][s] = *(const bf16x8*)(P + (mt * 16 + l15) * PROW + s * 32 + quad * 8);

        // l' += P * ones (row sums on the MFMA pipe; D row = query quad*4+r)
        #pragma unroll
        for (int s = 0; s < 4; ++s)
            #pragma unroll
            for (int mt = 0; mt < 4; ++mt)
                oaccL[mt] = __builtin_amdgcn_mfma_f32_16x16x32_bf16(pa[mt][s], ones, oaccL[mt], 0, 0, 0);

        // O' += P V over 4 k-steps of 32 keys; V fragment shared across 4 q-tiles
        #pragma unroll
        for (int t = 0; t < 4; ++t) {
            bf16x8 vf[4];
            #pragma unroll
            for (int s = 0; s < 4; ++s)
                vf[s] = *(const bf16x8*)(vbase + (size_t)(t * 16 + l15) * T_SEQ + key0 + s * 32 + quad * 8);
            #pragma unroll
            for (int s = 0; s < 4; ++s)
                #pragma unroll
                for (int mt = 0; mt < 4; ++mt)
                    oacc[mt][t] = __builtin_amdgcn_mfma_f32_16x16x32_bf16(pa[mt][s], vf[s], oacc[mt][t], 0, 0, 0);
        }
    }

    // parallel combine: every wave stores its full 64-row partial into its own region
    // (aliases P; all P reads done), one barrier, then wave w finalizes rows [16w,16w+16).
    float* Ocomb = (float*)(arena + 8192);            // [4][64][OPAD]
    float* Lcomb = (float*)(arena + 8192 + 69632);    // [4][64]

    __syncthreads();
    {
        float* Ow = Ocomb + wave * (64 * OPAD);
        #pragma unroll
        for (int mt = 0; mt < 4; ++mt) {
            #pragma unroll
            for (int t = 0; t < 4; ++t)
                #pragma unroll
                for (int r = 0; r < 4; ++r)
                    Ow[(mt * 16 + quad * 4 + r) * OPAD + t * 16 + l15] = oacc[mt][t][r];
            // l' is in C/D layout: query = quad*4 + r, duplicated across the 16 cols (l15)
            if (l15 == 0) {
                #pragma unroll
                for (int r = 0; r < 4; ++r)
                    Lcomb[wave * 64 + mt * 16 + quad * 4 + r] = oaccL[mt][r];
            }
        }
    }
    __syncthreads();
    {
        const int mt = wave;   // this wave finalizes queries [q0+16*wave, q0+16*wave+16)
        #pragma unroll
        for (int r = 0; r < 4; ++r) {
            const int rw = mt * 16 + quad * 4 + r;
            const int qpos = q0 + rw;
            float lv = 0.f;
            #pragma unroll
            for (int wv = 0; wv < 4; ++wv) lv += Lcomb[wv * 64 + rw];
            const bool qvalid = biasS[qpos] == 0.f;   // query mask == pm[b][t]
            const float inv = (qvalid && lv > 0.f) ? 1.f / lv : 0.f;
            #pragma unroll
            for (int t = 0; t < 4; ++t) {
                float o = 0.f;
                #pragma unroll
                for (int wv = 0; wv < 4; ++wv)
                    o += Ocomb[wv * (64 * OPAD) + rw * OPAD + t * 16 + l15];
                out[(bT + qpos) * H_DIM + t * 16 + l15] = o * inv;
            }
        }
    }
}

extern "C" void kernel_launch(void* const* d_in, const int* in_sizes, int n_in,
                              void* d_out, int out_size, void* d_ws, size_t ws_size,
                              hipStream_t stream) {
    const float* x  = (const float*)d_in[0];
    const int* pm   = (const int*)d_in[1];
    const float* Wk = (const float*)d_in[2];
    const float* Wq = (const float*)d_in[3];
    const float* Wv = (const float*)d_in[4];
    float* out = (float*)d_out;

    // ws: qb | kb | vT (bf16, 4MB each) | WtF (76.8KB)
    __bf16* qb  = (__bf16*)d_ws;
    __bf16* kb  = qb + QKV_ELEMS;
    __bf16* vT  = kb + QKV_ELEMS;
    __bf16* WtF = vT + QKV_ELEMS;

    prep_w<<<dim3((WTF_ELEMS + 255) / 256), dim3(256), 0, stream>>>(Wk, Wq, Wv, WtF);
    qkv_proj<<<dim3(BT_TOT / 64), dim3(256), 0, stream>>>(x, WtF, qb, kb, vT);
    attn<<<dim3(T_SEQ / 64, 16), dim3(256), 0, stream>>>(qb, kb, vT, pm, out);
}